// Round 1
// baseline (353.367 us; speedup 1.0000x reference)
//
#include <hip/hip_runtime.h>

namespace {

constexpr int kB = 16384;
constexpr int kC = 4;
constexpr int kH = 8;
constexpr int kT = 120;
constexpr float kAlpha  = 0.2f;
constexpr float kDT     = 10.0f;
constexpr float kThresh = 0.5f;
constexpr float kNever  = (float)kT * kDT;   // 1200.0f

__device__ __forceinline__ float fast_tanh(float x) {
    // tanh(x) = 1 - 2/(exp(2x)+1).  exp via native v_exp_f32 path, rcp via v_rcp_f32.
    float e = __expf(x + x);
#if defined(__has_builtin) && __has_builtin(__builtin_amdgcn_rcpf)
    float r = __builtin_amdgcn_rcpf(e + 1.0f);
    return fmaf(-2.0f, r, 1.0f);
#else
    return 1.0f - __fdividef(2.0f, e + 1.0f);
#endif
}

__global__ __launch_bounds__(256) void acc_rnn_kernel(
    const float* __restrict__ logits,      // [B,C]
    const float* __restrict__ p_iscale,    // [1]
    const float* __restrict__ p_nstd,      // [1]
    const float* __restrict__ ipw_,        // [H,1]
    const float* __restrict__ ipb_,        // [H]
    const float* __restrict__ spw_,        // [H,H]
    const float* __restrict__ cpw_,        // [H,1]
    const float* __restrict__ evw_,        // [1,H]
    const float* __restrict__ evb_,        // [1]
    const float* __restrict__ cbias_,      // [C,H]
    const float* __restrict__ compmat_,    // [C,C]
    const float* __restrict__ noise_,      // [T,B,C,H]
    float* __restrict__ out)               // [B,C]
{
    const int tid = blockIdx.x * 256 + threadIdx.x;   // tid = b*C + c
    const int c   = tid & (kC - 1);

    const float iscale = p_iscale[0];
    const float nstd   = p_nstd[0];
    const float evb    = evb_[0];

    // Wave-uniform weights -> compiler scalarizes to SGPRs.
    float W[kH][kH], cpw[kH], evw[kH];
#pragma unroll
    for (int k = 0; k < kH; ++k) {
        cpw[k] = cpw_[k];
        evw[k] = evw_[k];
#pragma unroll
        for (int h = 0; h < kH; ++h) W[k][h] = spw_[k * kH + h];
    }

    // Competition column for this lane's class: comp[c] = sum_{c'} ev[c'] * M[c', c].
    // e_j gathered via shfl_xor(j) holds ev of class (c^j) -> weight M[c^j, c].
    const float mw0 = compmat_[(c ^ 0) * kC + c];
    const float mw1 = compmat_[(c ^ 1) * kC + c];
    const float mw2 = compmat_[(c ^ 2) * kC + c];
    const float mw3 = compmat_[(c ^ 3) * kC + c];

    // Input embedding (constant over time): relu(logit*scale)*ipw + ipb + class_bias
    float rl = logits[tid] * iscale;
    rl = rl > 0.0f ? rl : 0.0f;
    float inp[kH];
#pragma unroll
    for (int k = 0; k < kH; ++k)
        inp[k] = fmaf(rl, ipw_[k], ipb_[k] + cbias_[c * kH + k]);

    float s[kH];
#pragma unroll
    for (int k = 0; k < kH; ++k) s[k] = 0.0f;
    // ev(state0) = 0·evw + evb; end-of-step new_ev == next step's ev, so carry it.
    float ev = evb;

    // Noise: lane tid owns the contiguous 32B slice noise[t][b][c][0:8].
    const float4* np4 = (const float4*)noise_;
    const int stepStride = kB * kC * kH / 4;   // 131072 float4 per time step
    const int lane = tid * 2;

    // 3-deep prefetch ring (T=120 divisible by 3).
    float4 nb[3][2];
#pragma unroll
    for (int j = 0; j < 3; ++j) {
        nb[j][0] = np4[j * stepStride + lane];
        nb[j][1] = np4[j * stepStride + lane + 1];
    }

    float tdec = kNever;

    for (int t0 = 0; t0 < kT; t0 += 3) {
#pragma unroll
        for (int j = 0; j < 3; ++j) {
            const int t = t0 + j;

            // competition from (carried) evidence
            float e1 = __shfl_xor(ev, 1, 64);
            float e2 = __shfl_xor(ev, 2, 64);
            float e3 = __shfl_xor(e1, 2, 64);
            float comp = ev * mw0;
            comp = fmaf(e1, mw1, comp);
            comp = fmaf(e2, mw2, comp);
            comp = fmaf(e3, mw3, comp);

            float nz[kH] = {nb[j][0].x, nb[j][0].y, nb[j][0].z, nb[j][0].w,
                            nb[j][1].x, nb[j][1].y, nb[j][1].z, nb[j][1].w};

            // prefetch noise for step t+3 (uniform branch)
            if (t + 3 < kT) {
                nb[j][0] = np4[(t + 3) * stepStride + lane];
                nb[j][1] = np4[(t + 3) * stepStride + lane + 1];
            }

            // cand_k = tanh( sum_h s[h]*W[k][h] + inp[k] + comp*cpw[k] + nz[k]*std )
            float cand[kH];
#pragma unroll
            for (int k = 0; k < kH; ++k) {
                float a = fmaf(comp, cpw[k], inp[k]);
                a = fmaf(nz[k], nstd, a);
#pragma unroll
                for (int h = 0; h < kH; ++h) a = fmaf(s[h], W[k][h], a);
                cand[k] = fast_tanh(a);
            }

            // state update + new evidence
            float nev = evb;
#pragma unroll
            for (int k = 0; k < kH; ++k) {
                s[k] = fmaf(kAlpha, cand[k] - s[k], s[k]);
                nev = fmaf(s[k], evw[k], nev);
            }
            ev = nev;

            // first-crossing time, branchless (times are increasing -> min works)
            float tc = (float)(t + 1) * kDT;
            tdec = fminf(tdec, ev > kThresh ? tc : kNever);
        }
    }

    out[tid] = tdec / 1000.0f;
}

}  // namespace

extern "C" void kernel_launch(void* const* d_in, const int* in_sizes, int n_in,
                              void* d_out, int out_size, void* d_ws, size_t ws_size,
                              hipStream_t stream) {
    (void)in_sizes; (void)n_in; (void)d_ws; (void)ws_size; (void)out_size;
    const float* logits   = (const float*)d_in[0];
    const float* iscale   = (const float*)d_in[1];
    const float* nstd     = (const float*)d_in[2];
    const float* ipw      = (const float*)d_in[3];
    const float* ipb      = (const float*)d_in[4];
    const float* spw      = (const float*)d_in[5];
    const float* cpw      = (const float*)d_in[6];
    const float* evw      = (const float*)d_in[7];
    const float* evb      = (const float*)d_in[8];
    const float* cbias    = (const float*)d_in[9];
    const float* compmat  = (const float*)d_in[10];
    const float* noise    = (const float*)d_in[11];
    float* out = (float*)d_out;

    dim3 grid(kB * kC / 256), block(256);
    acc_rnn_kernel<<<grid, block, 0, stream>>>(
        logits, iscale, nstd, ipw, ipb, spw, cpw, evw, evb,
        cbias, compmat, noise, out);
}